// Round 2
// baseline (354.160 us; speedup 1.0000x reference)
//
#include <hip/hip_runtime.h>

typedef unsigned short u16;
typedef unsigned int u32;
typedef __attribute__((ext_vector_type(8))) short s16x8;
typedef __attribute__((ext_vector_type(4))) float f32x4;

#define MFMA16(a,b,c) __builtin_amdgcn_mfma_f32_16x16x32_bf16(a,b,c,0,0,0)

__device__ __forceinline__ u16 f2bf(float f){
  u32 u = __builtin_bit_cast(u32, f);
  return (u16)((u + 0x7FFFu + ((u >> 16) & 1u)) >> 16);
}
__device__ __forceinline__ float b2f(u16 s){
  u32 u = ((u32)s) << 16;
  return __builtin_bit_cast(float, u);
}
// XOR-swizzled element index for [row][64] bf16 LDS tiles (8-elem groups)
__device__ __forceinline__ int sw64(int row, int col){
  return row * 64 + ((((col >> 3) ^ row) & 7) << 3) + (col & 7);
}
__device__ __forceinline__ void async16(const void* g, void* l){
  __builtin_amdgcn_global_load_lds((const __attribute__((address_space(1))) u32*)g,
                                   (__attribute__((address_space(3))) u32*)l, 16, 0, 0);
}

// B=4, N=4096, C=512, H=8, d=64, K=64. Tokens M=16384, out-channels OC=2048.
// QKVV ws layout: [o][m], o = g*512 + h*64 + dd (g: q,k,vCA,vSA), m = b*4096 + n.

// ---- kernel 0: convert x,W -> bf16; EF -> bf16 transposed [64][4096] ----
__global__ __launch_bounds__(256) void k_convert(const float4* __restrict__ x4,
                                                 const float4* __restrict__ w4,
                                                 const float* __restrict__ EF,
                                                 u16* __restrict__ Xb, u16* __restrict__ Wb,
                                                 u16* __restrict__ EFt){
  int i = blockIdx.x * 256 + threadIdx.x;
  if (i < 2097152){
    float4 v = x4[i];
    u32 lo = (u32)f2bf(v.x) | ((u32)f2bf(v.y) << 16);
    u32 hi = (u32)f2bf(v.z) | ((u32)f2bf(v.w) << 16);
    *(uint2*)(&Xb[(size_t)i*4]) = make_uint2(lo, hi);
  } else if (i < 2097152 + 262144){
    int j = i - 2097152;
    float4 v = w4[j];
    u32 lo = (u32)f2bf(v.x) | ((u32)f2bf(v.y) << 16);
    u32 hi = (u32)f2bf(v.z) | ((u32)f2bf(v.w) << 16);
    *(uint2*)(&Wb[(size_t)j*4]) = make_uint2(lo, hi);
  } else if (i < 2097152 + 262144 + 262144){
    int j = i - 2097152 - 262144;
    int kk = j >> 12, nn = j & 4095;
    EFt[(size_t)kk*4096 + nn] = f2bf(EF[(size_t)nn*64 + kk]);
  }
}

// ---- kernel 1: QKVV GEMM, Out[o][m] = sum_c Wb[o][c]*Xb[m][c], bf16 out ----
__global__ __launch_bounds__(256) void k_gemm(const u16* __restrict__ Wb,
                                              const u16* __restrict__ Xb,
                                              u16* __restrict__ Out){
  __shared__ u16 smA[128*32];
  __shared__ u16 smB[128*32];
  int bid = blockIdx.x;
  int ot = bid & 15, mt = bid >> 4;
  int o0 = ot * 128, m0 = mt * 128;
  int t = threadIdx.x;
  int lane = t & 63, w = t >> 6;
  int wr = w >> 1, wc = w & 1;
  int l15 = lane & 15, l4 = lane >> 4;
  f32x4 acc[4][4];
#pragma unroll
  for (int a = 0; a < 4; ++a)
#pragma unroll
    for (int b = 0; b < 4; ++b) acc[a][b] = (f32x4){0.f, 0.f, 0.f, 0.f};

  for (int kt = 0; kt < 16; ++kt){
    int kb = kt * 32;
#pragma unroll
    for (int i = 0; i < 2; ++i){
      int la = t + 256 * i;
      async16(Wb + (size_t)(o0 + (la >> 2)) * 512 + kb + (la & 3) * 8, &smA[la * 8]);
      async16(Xb + (size_t)(m0 + (la >> 2)) * 512 + kb + (la & 3) * 8, &smB[la * 8]);
    }
    __syncthreads();
    s16x8 af[4], bfr[4];
#pragma unroll
    for (int rf = 0; rf < 4; ++rf) af[rf] = *(const s16x8*)(&smA[(wr*64 + rf*16 + l15)*32 + l4*8]);
#pragma unroll
    for (int cf = 0; cf < 4; ++cf) bfr[cf] = *(const s16x8*)(&smB[(wc*64 + cf*16 + l15)*32 + l4*8]);
#pragma unroll
    for (int rf = 0; rf < 4; ++rf)
#pragma unroll
      for (int cf = 0; cf < 4; ++cf)
        acc[rf][cf] = MFMA16(af[rf], bfr[cf], acc[rf][cf]);
    __syncthreads();
  }
#pragma unroll
  for (int rf = 0; rf < 4; ++rf)
#pragma unroll
    for (int cf = 0; cf < 4; ++cf){
      int o = o0 + wr*64 + rf*16 + l4*4;
      int m = m0 + wc*64 + cf*16 + l15;
#pragma unroll
      for (int r = 0; r < 4; ++r) Out[(size_t)(o + r) * 16384 + m] = f2bf(acc[rf][cf][r]);
    }
}

// ---- kernel 2: reciprocal L2 norms of q,k rows over token axis ----
__global__ __launch_bounds__(64) void k_rnorm(const u16* __restrict__ QK,
                                              float* __restrict__ rq, float* __restrict__ rk){
  int bid = blockIdx.x;          // 4096 = 1024 rows * 4 batches
  int o = bid >> 2, b = bid & 3;
  int lane = threadIdx.x;
  const u16* row = QK + (size_t)o * 16384 + (size_t)b * 4096;
  float s = 0.f;
#pragma unroll
  for (int it = 0; it < 8; ++it){
    s16x8 v = *(const s16x8*)(&row[it * 512 + lane * 8]);
#pragma unroll
    for (int j = 0; j < 8; ++j){ float f = b2f((u16)v[j]); s += f * f; }
  }
  for (int off = 32; off; off >>= 1) s += __shfl_down(s, off);
  if (lane == 0){
    float r = 1.f / fmaxf(sqrtf(s), 1e-12f);
    if (o < 512) rq[b * 512 + o] = r;
    else         rk[b * 512 + (o - 512)] = r;
  }
}

// ---- kernel 3: k_proj (scaled by rq*temp2, stored transposed [kk][dd]) and v_proj ----
__global__ __launch_bounds__(256) void k_proj(const u16* __restrict__ QK,
                                              const u16* __restrict__ EFt,
                                              const float* __restrict__ rq,
                                              const float* __restrict__ t2,
                                              float* __restrict__ kpT, float* __restrict__ vp){
  int bid = blockIdx.x;          // 64 = which*32 + h*4 + b
  int b = bid & 3, h = (bid >> 2) & 7, which = bid >> 5;
  int o0 = (which ? 1536 : 512) + h * 64;
  size_t mbase = (size_t)b * 4096;
  int t = threadIdx.x, lane = t & 63, w = t >> 6, l15 = lane & 15, l4 = lane >> 4;
  f32x4 acc[4];
#pragma unroll
  for (int c = 0; c < 4; ++c) acc[c] = (f32x4){0.f,0.f,0.f,0.f};
  for (int ks = 0; ks < 128; ++ks){
    int n = ks * 32 + l4 * 8;
    s16x8 a = *(const s16x8*)(&QK[(size_t)(o0 + w*16 + l15) * 16384 + mbase + n]);
#pragma unroll
    for (int cf = 0; cf < 4; ++cf){
      s16x8 bb = *(const s16x8*)(&EFt[(size_t)(cf*16 + l15) * 4096 + n]);
      acc[cf] = MFMA16(a, bb, acc[cf]);
    }
  }
  int bh = b * 8 + h;
#pragma unroll
  for (int cf = 0; cf < 4; ++cf)
#pragma unroll
    for (int r = 0; r < 4; ++r){
      int dd = w*16 + l4*4 + r, kk = cf*16 + l15;
      float v = acc[cf][r];
      if (which == 0) kpT[((size_t)bh*64 + kk)*64 + dd] = v * rq[b*512 + h*64 + dd] * t2[h];
      else            vp [((size_t)bh*64 + dd)*64 + kk] = v;
    }
}

// ---- kernel 4a: channel attention S + softmax -> Pca (bf16) ----
__global__ __launch_bounds__(256) void k_ca_attn(const u16* __restrict__ QK,
                                                 const float* __restrict__ rq,
                                                 const float* __restrict__ rk,
                                                 const float* __restrict__ t1,
                                                 u16* __restrict__ Pca){
  __shared__ float S[64*64];
  int bid = blockIdx.x;          // 32 = h*4 + b
  int b = bid & 3, h = bid >> 2;
  size_t mbase = (size_t)b * 4096;
  int t = threadIdx.x, lane = t & 63, w = t >> 6, l15 = lane & 15, l4 = lane >> 4;
  f32x4 acc[4];
#pragma unroll
  for (int c = 0; c < 4; ++c) acc[c] = (f32x4){0.f,0.f,0.f,0.f};
  int oq = h*64 + w*16 + l15;
  for (int ks = 0; ks < 128; ++ks){
    int m = ks * 32 + l4 * 8;
    s16x8 a = *(const s16x8*)(&QK[(size_t)oq * 16384 + mbase + m]);
#pragma unroll
    for (int cf = 0; cf < 4; ++cf){
      s16x8 kb = *(const s16x8*)(&QK[(size_t)(512 + h*64 + cf*16 + l15) * 16384 + mbase + m]);
      acc[cf] = MFMA16(a, kb, acc[cf]);
    }
  }
  float tmp = t1[h];
#pragma unroll
  for (int cf = 0; cf < 4; ++cf)
#pragma unroll
    for (int r = 0; r < 4; ++r){
      int d = w*16 + l4*4 + r, e = cf*16 + l15;
      S[d*64 + e] = acc[cf][r] * rq[b*512 + h*64 + d] * rk[b*512 + h*64 + e] * tmp;
    }
  __syncthreads();
  if (t < 64){
    float mx = -1e30f;
    for (int it = 0; it < 64; ++it){ int e = (t + it) & 63; mx = fmaxf(mx, S[t*64 + e]); }
    float sum = 0.f;
    for (int it = 0; it < 64; ++it){ int e = (t + it) & 63; sum += __expf(S[t*64 + e] - mx); }
    float inv = 1.f / sum;
    for (int it = 0; it < 64; ++it){
      int e = (t + it) & 63;
      Pca[((size_t)(b*8 + h) * 64 + t) * 64 + e] = f2bf(__expf(S[t*64 + e] - mx) * inv);
    }
  }
}

// ---- kernel 4b: x_CA = P @ V_CA per 64-token chunk; overwrite out[b][n][h*64+dd] ----
__global__ __launch_bounds__(256) void k_ca_pv(const u16* __restrict__ QK,
                                               const u16* __restrict__ Pca,
                                               float* __restrict__ out){
  __shared__ u16 Pl[64*64];
  __shared__ u16 Vt[64*64];
  __shared__ float Sx[64*64];
  int bid = blockIdx.x;          // 2048 = bh*64 + ch
  int ch = bid & 63, bh = bid >> 6, b = bh >> 3, h = bh & 7;
  int n0 = ch * 64;
  int t = threadIdx.x, lane = t & 63, w = t >> 6, l15 = lane & 15, l4 = lane >> 4;
#pragma unroll
  for (int i = 0; i < 16; ++i){
    int idx = t + 256 * i;
    Pl[sw64(idx >> 6, idx & 63)] = Pca[(size_t)bh * 4096 + idx];
    int e = idx >> 6, j = idx & 63;
    Vt[sw64(j, e)] = QK[(size_t)(1024 + h*64 + e) * 16384 + (size_t)b*4096 + n0 + j];
  }
  __syncthreads();
  f32x4 acc[4];
#pragma unroll
  for (int c = 0; c < 4; ++c) acc[c] = (f32x4){0.f,0.f,0.f,0.f};
#pragma unroll
  for (int ks = 0; ks < 2; ++ks){
    s16x8 a = *(const s16x8*)(&Pl[sw64(w*16 + l15, ks*32 + l4*8)]);
#pragma unroll
    for (int cf = 0; cf < 4; ++cf){
      s16x8 bb = *(const s16x8*)(&Vt[sw64(cf*16 + l15, ks*32 + l4*8)]);
      acc[cf] = MFMA16(a, bb, acc[cf]);
    }
  }
#pragma unroll
  for (int cf = 0; cf < 4; ++cf)
#pragma unroll
    for (int r = 0; r < 4; ++r){
      int d = w*16 + l4*4 + r, j = cf*16 + l15;
      Sx[j*64 + d] = acc[cf][r];
    }
  __syncthreads();
#pragma unroll
  for (int i = 0; i < 4; ++i){
    int idx = t + 256 * i;       // 1024 float4s
    int j = idx >> 4, v = idx & 15;
    float4 val;
    val.x = Sx[j*64 + v*4 + 0]; val.y = Sx[j*64 + v*4 + 1];
    val.z = Sx[j*64 + v*4 + 2]; val.w = Sx[j*64 + v*4 + 3];
    *(float4*)(&out[((size_t)(b*4096 + n0 + j)) * 512 + h*64 + v*4]) = val;
  }
}

// ---- kernel 5: spatial attention per 64-token chunk; out += with faithful-bug scatter ----
__global__ __launch_bounds__(256) void k_sa(const u16* __restrict__ QK,
                                            const float* __restrict__ kpT,
                                            const float* __restrict__ vpw,
                                            float* __restrict__ out){
  __shared__ u16 Qt[64*64];      // Q tile, then reused as P (bf16)
  __shared__ float Sf[64*64];    // S, then reused as x_SA^T
  __shared__ u16 kpl[64*64];     // [kk][dd]
  __shared__ u16 vpl[64*64];     // [dd][kk]
  int bid = blockIdx.x;          // 2048 = bh*64 + ch
  int ch = bid & 63, bh = bid >> 6, b = bh >> 3, h = bh & 7;
  int n0 = ch * 64;
  int t = threadIdx.x, lane = t & 63, w = t >> 6, l15 = lane & 15, l4 = lane >> 4;
#pragma unroll
  for (int i = 0; i < 16; ++i){
    int idx = t + 256 * i;
    int row = idx >> 6, col = idx & 63;
    kpl[sw64(row, col)] = f2bf(kpT[(size_t)bh * 4096 + idx]);
    vpl[sw64(row, col)] = f2bf(vpw[(size_t)bh * 4096 + idx]);
    int dd = row, j = col;
    Qt[sw64(j, dd)] = QK[(size_t)(h*64 + dd) * 16384 + (size_t)b*4096 + n0 + j];
  }
  __syncthreads();
  f32x4 acc[4];
#pragma unroll
  for (int c = 0; c < 4; ++c) acc[c] = (f32x4){0.f,0.f,0.f,0.f};
#pragma unroll
  for (int ks = 0; ks < 2; ++ks){
    s16x8 a = *(const s16x8*)(&Qt[sw64(w*16 + l15, ks*32 + l4*8)]);
#pragma unroll
    for (int cf = 0; cf < 4; ++cf){
      s16x8 bb = *(const s16x8*)(&kpl[sw64(cf*16 + l15, ks*32 + l4*8)]);
      acc[cf] = MFMA16(a, bb, acc[cf]);
    }
  }
#pragma unroll
  for (int cf = 0; cf < 4; ++cf)
#pragma unroll
    for (int r = 0; r < 4; ++r){
      int j = w*16 + l4*4 + r, kk = cf*16 + l15;
      Sf[j*64 + kk] = acc[cf][r];
    }
  __syncthreads();
  if (t < 64){
    float mx = -1e30f;
    for (int it = 0; it < 64; ++it){ int kk = (t + it) & 63; mx = fmaxf(mx, Sf[t*64 + kk]); }
    float sum = 0.f;
    for (int it = 0; it < 64; ++it){ int kk = (t + it) & 63; sum += __expf(Sf[t*64 + kk] - mx); }
    float inv = 1.f / sum;
    for (int it = 0; it < 64; ++it){
      int kk = (t + it) & 63;
      Qt[sw64(t, kk)] = f2bf(__expf(Sf[t*64 + kk] - mx) * inv);
    }
  }
  __syncthreads();
  f32x4 acc2[4];
#pragma unroll
  for (int c = 0; c < 4; ++c) acc2[c] = (f32x4){0.f,0.f,0.f,0.f};
#pragma unroll
  for (int ks = 0; ks < 2; ++ks){
    s16x8 a = *(const s16x8*)(&Qt[sw64(w*16 + l15, ks*32 + l4*8)]);
#pragma unroll
    for (int cf = 0; cf < 4; ++cf){
      s16x8 bb = *(const s16x8*)(&vpl[sw64(cf*16 + l15, ks*32 + l4*8)]);
      acc2[cf] = MFMA16(a, bb, acc2[cf]);
    }
  }
#pragma unroll
  for (int cf = 0; cf < 4; ++cf)
#pragma unroll
    for (int r = 0; r < 4; ++r){
      int j = w*16 + l4*4 + r, dd = cf*16 + l15;
      Sf[dd*64 + j] = acc2[cf][r];   // x_SA^T [dd][j]
    }
  __syncthreads();
  // faithful-bug scatter: out[b, dd*32768 + h*4096 + n0 + j] += x_SA[n][dd]
#pragma unroll
  for (int i = 0; i < 4; ++i){
    int idx = t + 256 * i;           // 1024 float4s
    int dd = idx >> 4, v = idx & 15;
    size_t p = (size_t)b*2097152 + (size_t)dd*32768 + (size_t)h*4096 + n0 + v*4;
    float4 cur = *(float4*)(&out[p]);
    cur.x += Sf[dd*64 + v*4 + 0]; cur.y += Sf[dd*64 + v*4 + 1];
    cur.z += Sf[dd*64 + v*4 + 2]; cur.w += Sf[dd*64 + v*4 + 3];
    *(float4*)(&out[p]) = cur;
  }
}

extern "C" void kernel_launch(void* const* d_in, const int* in_sizes, int n_in,
                              void* d_out, int out_size, void* d_ws, size_t ws_size,
                              hipStream_t stream) {
  const float* x  = (const float*)d_in[0];
  const float* Wq = (const float*)d_in[1];
  const float* EF = (const float*)d_in[2];
  const float* t1 = (const float*)d_in[3];
  const float* t2 = (const float*)d_in[4];
  float* out = (float*)d_out;

  u16* Xb  = (u16*)d_ws;                 // 16384*512
  u16* Wb  = Xb + 8388608;               // 2048*512
  u16* EFt = Wb + 1048576;               // 64*4096
  u16* QK  = EFt + 262144;               // 2048*16384
  float* rq  = (float*)(QK + 33554432);  // 4*512
  float* rk  = rq + 2048;                // 4*512
  float* kpT = rk + 2048;                // 32*64*64  [bh][kk][dd], pre-scaled rq*t2
  float* vp  = kpT + 131072;             // 32*64*64  [bh][dd][kk]
  u16* Pca   = (u16*)(vp + 131072);      // 32*64*64 bf16

  k_convert<<<10240, 256, 0, stream>>>((const float4*)x, (const float4*)Wq, EF, Xb, Wb, EFt);
  k_gemm   <<<2048, 256, 0, stream>>>(Wb, Xb, QK);
  k_rnorm  <<<4096, 64, 0, stream>>>(QK, rq, rk);
  k_proj   <<<64,   256, 0, stream>>>(QK, EFt, rq, t2, kpT, vp);
  k_ca_attn<<<32,   256, 0, stream>>>(QK, rq, rk, t1, Pca);
  k_ca_pv  <<<2048, 256, 0, stream>>>(QK, Pca, out);
  k_sa     <<<2048, 256, 0, stream>>>(QK, kpT, vp, out);
}

// Round 3
// 221.576 us; speedup vs baseline: 1.5984x; 1.5984x over previous
//
#include <hip/hip_runtime.h>

typedef unsigned short u16;
typedef unsigned int u32;
typedef __attribute__((ext_vector_type(8))) short s16x8;
typedef __attribute__((ext_vector_type(4))) float f32x4;

#define MFMA16(a,b,c) __builtin_amdgcn_mfma_f32_16x16x32_bf16(a,b,c,0,0,0)

__device__ __forceinline__ u16 f2bf(float f){
  u32 u = __builtin_bit_cast(u32, f);
  return (u16)((u + 0x7FFFu + ((u >> 16) & 1u)) >> 16);
}
__device__ __forceinline__ float b2f(u16 s){
  u32 u = ((u32)s) << 16;
  return __builtin_bit_cast(float, u);
}
// XOR-swizzled element index for [row][64] bf16 LDS tiles (8-elem groups)
__device__ __forceinline__ int sw64(int row, int col){
  return row * 64 + ((((col >> 3) ^ row) & 7) << 3) + (col & 7);
}
__device__ __forceinline__ void async16(const void* g, void* l){
  __builtin_amdgcn_global_load_lds((const __attribute__((address_space(1))) u32*)g,
                                   (__attribute__((address_space(3))) u32*)l, 16, 0, 0);
}

// B=4, N=4096, C=512, H=8, d=64, K=64. Tokens M=16384, out-channels OC=2048.
// QKVV ws layout: [o][m], o = g*512 + h*64 + dd (g: q,k,vCA,vSA), m = b*4096 + n.

// ---- kernel 0: convert x,W -> bf16; EF -> bf16 transposed [64][4096] ----
__global__ __launch_bounds__(256) void k_convert(const float4* __restrict__ x4,
                                                 const float4* __restrict__ w4,
                                                 const float* __restrict__ EF,
                                                 u16* __restrict__ Xb, u16* __restrict__ Wb,
                                                 u16* __restrict__ EFt){
  int i = blockIdx.x * 256 + threadIdx.x;
  if (i < 2097152){
    float4 v = x4[i];
    u32 lo = (u32)f2bf(v.x) | ((u32)f2bf(v.y) << 16);
    u32 hi = (u32)f2bf(v.z) | ((u32)f2bf(v.w) << 16);
    *(uint2*)(&Xb[(size_t)i*4]) = make_uint2(lo, hi);
  } else if (i < 2097152 + 262144){
    int j = i - 2097152;
    float4 v = w4[j];
    u32 lo = (u32)f2bf(v.x) | ((u32)f2bf(v.y) << 16);
    u32 hi = (u32)f2bf(v.z) | ((u32)f2bf(v.w) << 16);
    *(uint2*)(&Wb[(size_t)j*4]) = make_uint2(lo, hi);
  } else if (i < 2097152 + 262144 + 262144){
    int j = i - 2097152 - 262144;
    int kk = j >> 12, nn = j & 4095;
    EFt[(size_t)kk*4096 + nn] = f2bf(EF[(size_t)nn*64 + kk]);
  }
}

// ---- kernel 1: QKVV GEMM, Out[o][m] = sum_c Wb[o][c]*Xb[m][c], bf16 out ----
__global__ __launch_bounds__(256) void k_gemm(const u16* __restrict__ Wb,
                                              const u16* __restrict__ Xb,
                                              u16* __restrict__ Out){
  __shared__ u16 smA[128*32];
  __shared__ u16 smB[128*32];
  int bid = blockIdx.x;
  int ot = bid & 15, mt = bid >> 4;
  int o0 = ot * 128, m0 = mt * 128;
  int t = threadIdx.x;
  int lane = t & 63, w = t >> 6;
  int wr = w >> 1, wc = w & 1;
  int l15 = lane & 15, l4 = lane >> 4;
  f32x4 acc[4][4];
#pragma unroll
  for (int a = 0; a < 4; ++a)
#pragma unroll
    for (int b = 0; b < 4; ++b) acc[a][b] = (f32x4){0.f, 0.f, 0.f, 0.f};

  for (int kt = 0; kt < 16; ++kt){
    int kb = kt * 32;
#pragma unroll
    for (int i = 0; i < 2; ++i){
      int la = t + 256 * i;
      async16(Wb + (size_t)(o0 + (la >> 2)) * 512 + kb + (la & 3) * 8, &smA[la * 8]);
      async16(Xb + (size_t)(m0 + (la >> 2)) * 512 + kb + (la & 3) * 8, &smB[la * 8]);
    }
    __syncthreads();
    s16x8 af[4], bfr[4];
#pragma unroll
    for (int rf = 0; rf < 4; ++rf) af[rf] = *(const s16x8*)(&smA[(wr*64 + rf*16 + l15)*32 + l4*8]);
#pragma unroll
    for (int cf = 0; cf < 4; ++cf) bfr[cf] = *(const s16x8*)(&smB[(wc*64 + cf*16 + l15)*32 + l4*8]);
#pragma unroll
    for (int rf = 0; rf < 4; ++rf)
#pragma unroll
      for (int cf = 0; cf < 4; ++cf)
        acc[rf][cf] = MFMA16(af[rf], bfr[cf], acc[rf][cf]);
    __syncthreads();
  }
#pragma unroll
  for (int rf = 0; rf < 4; ++rf)
#pragma unroll
    for (int cf = 0; cf < 4; ++cf){
      int o = o0 + wr*64 + rf*16 + l4*4;
      int m = m0 + wc*64 + cf*16 + l15;
#pragma unroll
      for (int r = 0; r < 4; ++r) Out[(size_t)(o + r) * 16384 + m] = f2bf(acc[rf][cf][r]);
    }
}

// ---- kernel 2: reciprocal L2 norms of q,k rows over token axis ----
__global__ __launch_bounds__(64) void k_rnorm(const u16* __restrict__ QK,
                                              float* __restrict__ rq, float* __restrict__ rk){
  int bid = blockIdx.x;          // 4096 = 1024 rows * 4 batches
  int o = bid >> 2, b = bid & 3;
  int lane = threadIdx.x;
  const u16* row = QK + (size_t)o * 16384 + (size_t)b * 4096;
  float s = 0.f;
#pragma unroll
  for (int it = 0; it < 8; ++it){
    s16x8 v = *(const s16x8*)(&row[it * 512 + lane * 8]);
#pragma unroll
    for (int j = 0; j < 8; ++j){ float f = b2f((u16)v[j]); s += f * f; }
  }
  for (int off = 32; off; off >>= 1) s += __shfl_down(s, off);
  if (lane == 0){
    float r = 1.f / fmaxf(sqrtf(s), 1e-12f);
    if (o < 512) rq[b * 512 + o] = r;
    else         rk[b * 512 + (o - 512)] = r;
  }
}

// ---- kernel 3: partial contractions over 512-token splits, no barriers/LDS ----
// grid 768 = p*256 + bh*8 + s;  p: 0 = q.kT, 1 = k.EF (store [kk][dd]), 2 = vSA.EF ([dd][kk])
// Pp[bh][p][s][4096] f32 partials (aliased on Xb region, dead after k_gemm)
__global__ __launch_bounds__(256) void k_acc1(const u16* __restrict__ QK,
                                              const u16* __restrict__ EFt,
                                              float* __restrict__ Pp){
  int bid = blockIdx.x;
  int p = bid >> 8;
  int rem = bid & 255;
  int bh = rem >> 3, s = rem & 7;
  int b = bh >> 3, h = bh & 7;
  int t = threadIdx.x, lane = t & 63, w = t >> 6, l15 = lane & 15, l4 = lane >> 4;
  int abase = (p == 0 ? 0 : (p == 1 ? 512 : 1536)) + h * 64;
  const u16* aptr = QK + (size_t)(abase + w*16 + l15) * 16384 + (size_t)b * 4096 + s * 512;
  f32x4 acc[4];
#pragma unroll
  for (int c = 0; c < 4; ++c) acc[c] = (f32x4){0.f,0.f,0.f,0.f};

  if (p == 0){
    const u16* bptr = QK + (size_t)(512 + h*64 + l15) * 16384 + (size_t)b * 4096 + s * 512;
#pragma unroll 2
    for (int ks = 0; ks < 16; ++ks){
      int n = ks * 32 + l4 * 8;
      s16x8 a = *(const s16x8*)(aptr + n);
#pragma unroll
      for (int cf = 0; cf < 4; ++cf){
        s16x8 bb = *(const s16x8*)(bptr + (size_t)cf * 16 * 16384 + n);
        acc[cf] = MFMA16(a, bb, acc[cf]);
      }
    }
  } else {
    const u16* bptr = EFt + (size_t)l15 * 4096 + s * 512;
#pragma unroll 2
    for (int ks = 0; ks < 16; ++ks){
      int n = ks * 32 + l4 * 8;
      s16x8 a = *(const s16x8*)(aptr + n);
#pragma unroll
      for (int cf = 0; cf < 4; ++cf){
        s16x8 bb = *(const s16x8*)(bptr + (size_t)cf * 16 * 4096 + n);
        acc[cf] = MFMA16(a, bb, acc[cf]);
      }
    }
  }

  float* out = Pp + ((size_t)(bh * 3 + p) * 8 + s) * 4096;
#pragma unroll
  for (int cf = 0; cf < 4; ++cf)
#pragma unroll
    for (int r = 0; r < 4; ++r){
      int rr = w*16 + l4*4 + r;        // A-row index of output
      int cc = cf*16 + l15;            // B-row index of output
      int off = (p == 1) ? (cc * 64 + rr) : (rr * 64 + cc);
      out[off] = acc[cf][r];
    }
}

// ---- kernel 4: reduce partials; scale; softmax(S)->Pca; kp*rq*t2->kpb; vp->vpb ----
// LDS-free: thread t owns row t>>2, col quarter t&3 (16 contiguous elements).
__global__ __launch_bounds__(256) void k_fin(const float* __restrict__ Pp,
                                             const float* __restrict__ rq,
                                             const float* __restrict__ rk,
                                             const float* __restrict__ t1,
                                             const float* __restrict__ t2,
                                             u16* __restrict__ Pca,
                                             u16* __restrict__ kpb,
                                             u16* __restrict__ vpb){
  int bh = blockIdx.x;
  int b = bh >> 3, h = bh & 7;
  int t = threadIdx.x;
  int row = t >> 2, q4 = t & 3;
  const float* base = Pp + (size_t)bh * 3 * 8 * 4096;
  float t1h = t1[h], t2h = t2[h];
  const float* rqh = rq + b*512 + h*64;
  const float* rkh = rk + b*512 + h*64;

  // ---- product 0: S = q.kT -> scale -> softmax -> Pca
  {
    float v[16];
#pragma unroll
    for (int i = 0; i < 4; ++i){
      f32x4 a = (f32x4){0.f,0.f,0.f,0.f};
#pragma unroll
      for (int s = 0; s < 8; ++s)
        a += *(const f32x4*)(base + (size_t)s * 4096 + t*16 + i*4);
#pragma unroll
      for (int j = 0; j < 4; ++j) v[i*4 + j] = a[j];
    }
    float sq = rqh[row] * t1h;
#pragma unroll
    for (int e = 0; e < 16; ++e) v[e] *= sq * rkh[q4*16 + e];
    float mx = v[0];
#pragma unroll
    for (int e = 1; e < 16; ++e) mx = fmaxf(mx, v[e]);
    mx = fmaxf(mx, __shfl_xor(mx, 1));
    mx = fmaxf(mx, __shfl_xor(mx, 2));
    float sum = 0.f;
#pragma unroll
    for (int e = 0; e < 16; ++e){ v[e] = __expf(v[e] - mx); sum += v[e]; }
    sum += __shfl_xor(sum, 1);
    sum += __shfl_xor(sum, 2);
    float inv = 1.f / sum;
    s16x8 o0, o1;
#pragma unroll
    for (int e = 0; e < 8; ++e){ o0[e] = (short)f2bf(v[e] * inv); o1[e] = (short)f2bf(v[8+e] * inv); }
    *(s16x8*)(&Pca[(size_t)bh*4096 + t*16])     = o0;
    *(s16x8*)(&Pca[(size_t)bh*4096 + t*16 + 8]) = o1;
  }
  // ---- product 1: kp [kk][dd], scale rq[dd]*t2
  {
    const float* p1 = base + 8 * 4096;
    float v[16];
#pragma unroll
    for (int i = 0; i < 4; ++i){
      f32x4 a = (f32x4){0.f,0.f,0.f,0.f};
#pragma unroll
      for (int s = 0; s < 8; ++s)
        a += *(const f32x4*)(p1 + (size_t)s * 4096 + t*16 + i*4);
#pragma unroll
      for (int j = 0; j < 4; ++j) v[i*4 + j] = a[j];
    }
    s16x8 o0, o1;
#pragma unroll
    for (int e = 0; e < 8; ++e){
      o0[e] = (short)f2bf(v[e]   * rqh[q4*16 + e]     * t2h);
      o1[e] = (short)f2bf(v[8+e] * rqh[q4*16 + 8 + e] * t2h);
    }
    *(s16x8*)(&kpb[(size_t)bh*4096 + t*16])     = o0;
    *(s16x8*)(&kpb[(size_t)bh*4096 + t*16 + 8]) = o1;
  }
  // ---- product 2: vp [dd][kk], no scale
  {
    const float* p2 = base + 16 * 4096;
    float v[16];
#pragma unroll
    for (int i = 0; i < 4; ++i){
      f32x4 a = (f32x4){0.f,0.f,0.f,0.f};
#pragma unroll
      for (int s = 0; s < 8; ++s)
        a += *(const f32x4*)(p2 + (size_t)s * 4096 + t*16 + i*4);
#pragma unroll
      for (int j = 0; j < 4; ++j) v[i*4 + j] = a[j];
    }
    s16x8 o0, o1;
#pragma unroll
    for (int e = 0; e < 8; ++e){ o0[e] = (short)f2bf(v[e]); o1[e] = (short)f2bf(v[8+e]); }
    *(s16x8*)(&vpb[(size_t)bh*4096 + t*16])     = o0;
    *(s16x8*)(&vpb[(size_t)bh*4096 + t*16 + 8]) = o1;
  }
}

// ---- kernel 5: x_CA = P @ V_CA per 64-token chunk; overwrite out[b][n][h*64+dd] ----
__global__ __launch_bounds__(256) void k_ca_pv(const u16* __restrict__ QK,
                                               const u16* __restrict__ Pca,
                                               float* __restrict__ out){
  __shared__ u16 Pl[64*64];
  __shared__ u16 Vt[64*64];
  __shared__ float Sx[64*64];
  int bid = blockIdx.x;          // 2048 = bh*64 + ch
  int ch = bid & 63, bh = bid >> 6, b = bh >> 3, h = bh & 7;
  int n0 = ch * 64;
  int t = threadIdx.x, lane = t & 63, w = t >> 6, l15 = lane & 15, l4 = lane >> 4;
#pragma unroll
  for (int i = 0; i < 16; ++i){
    int idx = t + 256 * i;
    Pl[sw64(idx >> 6, idx & 63)] = Pca[(size_t)bh * 4096 + idx];
    int e = idx >> 6, j = idx & 63;
    Vt[sw64(j, e)] = QK[(size_t)(1024 + h*64 + e) * 16384 + (size_t)b*4096 + n0 + j];
  }
  __syncthreads();
  f32x4 acc[4];
#pragma unroll
  for (int c = 0; c < 4; ++c) acc[c] = (f32x4){0.f,0.f,0.f,0.f};
#pragma unroll
  for (int ks = 0; ks < 2; ++ks){
    s16x8 a = *(const s16x8*)(&Pl[sw64(w*16 + l15, ks*32 + l4*8)]);
#pragma unroll
    for (int cf = 0; cf < 4; ++cf){
      s16x8 bb = *(const s16x8*)(&Vt[sw64(cf*16 + l15, ks*32 + l4*8)]);
      acc[cf] = MFMA16(a, bb, acc[cf]);
    }
  }
#pragma unroll
  for (int cf = 0; cf < 4; ++cf)
#pragma unroll
    for (int r = 0; r < 4; ++r){
      int d = w*16 + l4*4 + r, j = cf*16 + l15;
      Sx[j*64 + d] = acc[cf][r];
    }
  __syncthreads();
#pragma unroll
  for (int i = 0; i < 4; ++i){
    int idx = t + 256 * i;       // 1024 float4s
    int j = idx >> 4, v = idx & 15;
    float4 val;
    val.x = Sx[j*64 + v*4 + 0]; val.y = Sx[j*64 + v*4 + 1];
    val.z = Sx[j*64 + v*4 + 2]; val.w = Sx[j*64 + v*4 + 3];
    *(float4*)(&out[((size_t)(b*4096 + n0 + j)) * 512 + h*64 + v*4]) = val;
  }
}

// ---- kernel 6: spatial attention per 64-token chunk; out += with faithful-bug scatter ----
__global__ __launch_bounds__(256) void k_sa(const u16* __restrict__ QK,
                                            const u16* __restrict__ kpb,
                                            const u16* __restrict__ vpb,
                                            float* __restrict__ out){
  __shared__ u16 Qt[64*64];      // Q tile, then reused as P (bf16)
  __shared__ float Sf[64*64];    // S, then reused as x_SA^T
  __shared__ u16 kpl[64*64];     // [kk][dd]
  __shared__ u16 vpl[64*64];     // [dd][kk]
  int bid = blockIdx.x;          // 2048 = bh*64 + ch
  int ch = bid & 63, bh = bid >> 6, b = bh >> 3, h = bh & 7;
  int n0 = ch * 64;
  int t = threadIdx.x, lane = t & 63, w = t >> 6, l15 = lane & 15, l4 = lane >> 4;
#pragma unroll
  for (int i = 0; i < 16; ++i){
    int idx = t + 256 * i;
    int row = idx >> 6, col = idx & 63;
    kpl[sw64(row, col)] = kpb[(size_t)bh * 4096 + idx];
    vpl[sw64(row, col)] = vpb[(size_t)bh * 4096 + idx];
    int dd = row, j = col;
    Qt[sw64(j, dd)] = QK[(size_t)(h*64 + dd) * 16384 + (size_t)b*4096 + n0 + j];
  }
  __syncthreads();
  f32x4 acc[4];
#pragma unroll
  for (int c = 0; c < 4; ++c) acc[c] = (f32x4){0.f,0.f,0.f,0.f};
#pragma unroll
  for (int ks = 0; ks < 2; ++ks){
    s16x8 a = *(const s16x8*)(&Qt[sw64(w*16 + l15, ks*32 + l4*8)]);
#pragma unroll
    for (int cf = 0; cf < 4; ++cf){
      s16x8 bb = *(const s16x8*)(&kpl[sw64(cf*16 + l15, ks*32 + l4*8)]);
      acc[cf] = MFMA16(a, bb, acc[cf]);
    }
  }
#pragma unroll
  for (int cf = 0; cf < 4; ++cf)
#pragma unroll
    for (int r = 0; r < 4; ++r){
      int j = w*16 + l4*4 + r, kk = cf*16 + l15;
      Sf[j*64 + kk] = acc[cf][r];
    }
  __syncthreads();
  if (t < 64){
    float mx = -1e30f;
    for (int it = 0; it < 64; ++it){ int kk = (t + it) & 63; mx = fmaxf(mx, Sf[t*64 + kk]); }
    float sum = 0.f;
    for (int it = 0; it < 64; ++it){ int kk = (t + it) & 63; sum += __expf(Sf[t*64 + kk] - mx); }
    float inv = 1.f / sum;
    for (int it = 0; it < 64; ++it){
      int kk = (t + it) & 63;
      Qt[sw64(t, kk)] = f2bf(__expf(Sf[t*64 + kk] - mx) * inv);
    }
  }
  __syncthreads();
  f32x4 acc2[4];
#pragma unroll
  for (int c = 0; c < 4; ++c) acc2[c] = (f32x4){0.f,0.f,0.f,0.f};
#pragma unroll
  for (int ks = 0; ks < 2; ++ks){
    s16x8 a = *(const s16x8*)(&Qt[sw64(w*16 + l15, ks*32 + l4*8)]);
#pragma unroll
    for (int cf = 0; cf < 4; ++cf){
      s16x8 bb = *(const s16x8*)(&vpl[sw64(cf*16 + l15, ks*32 + l4*8)]);
      acc2[cf] = MFMA16(a, bb, acc2[cf]);
    }
  }
#pragma unroll
  for (int cf = 0; cf < 4; ++cf)
#pragma unroll
    for (int r = 0; r < 4; ++r){
      int j = w*16 + l4*4 + r, dd = cf*16 + l15;
      Sf[dd*64 + j] = acc2[cf][r];   // x_SA^T [dd][j]
    }
  __syncthreads();
  // faithful-bug scatter: out[b, dd*32768 + h*4096 + n0 + j] += x_SA[n][dd]
#pragma unroll
  for (int i = 0; i < 4; ++i){
    int idx = t + 256 * i;           // 1024 float4s
    int dd = idx >> 4, v = idx & 15;
    size_t p = (size_t)b*2097152 + (size_t)dd*32768 + (size_t)h*4096 + n0 + v*4;
    float4 cur = *(float4*)(&out[p]);
    cur.x += Sf[dd*64 + v*4 + 0]; cur.y += Sf[dd*64 + v*4 + 1];
    cur.z += Sf[dd*64 + v*4 + 2]; cur.w += Sf[dd*64 + v*4 + 3];
    *(float4*)(&out[p]) = cur;
  }
}

extern "C" void kernel_launch(void* const* d_in, const int* in_sizes, int n_in,
                              void* d_out, int out_size, void* d_ws, size_t ws_size,
                              hipStream_t stream) {
  const float* x  = (const float*)d_in[0];
  const float* Wq = (const float*)d_in[1];
  const float* EF = (const float*)d_in[2];
  const float* t1 = (const float*)d_in[3];
  const float* t2 = (const float*)d_in[4];
  float* out = (float*)d_out;

  u16* Xb  = (u16*)d_ws;                 // 16384*512 (dead after k_gemm)
  u16* Wb  = Xb + 8388608;               // 2048*512
  u16* EFt = Wb + 1048576;               // 64*4096
  u16* QK  = EFt + 262144;               // 2048*16384
  float* rq  = (float*)(QK + 33554432);  // 4*512
  float* rk  = rq + 2048;                // 4*512
  u16* kpb = (u16*)(rk + 2048);          // 32*64*64 bf16 [bh][kk][dd], pre-scaled rq*t2
  u16* vpb = kpb + 131072;               // 32*64*64 bf16 [bh][dd][kk]
  u16* Pca = vpb + 131072;               // 32*64*64 bf16
  float* Pp = (float*)d_ws;              // partials [bh][3][8][4096] f32, aliases Xb (12.6MB <= 16MB)

  k_convert<<<10240, 256, 0, stream>>>((const float4*)x, (const float4*)Wq, EF, Xb, Wb, EFt);
  k_gemm   <<<2048, 256, 0, stream>>>(Wb, Xb, QK);
  k_rnorm  <<<4096, 64, 0, stream>>>(QK, rq, rk);
  k_acc1   <<<768,  256, 0, stream>>>(QK, EFt, Pp);
  k_fin    <<<32,   256, 0, stream>>>(Pp, rq, rk, t1, t2, Pca, kpb, vpb);
  k_ca_pv  <<<2048, 256, 0, stream>>>(QK, Pca, out);
  k_sa     <<<2048, 256, 0, stream>>>(QK, kpb, vpb, out);
}

// Round 5
// 198.613 us; speedup vs baseline: 1.7832x; 1.1156x over previous
//
#include <hip/hip_runtime.h>

typedef unsigned short u16;
typedef unsigned int u32;
typedef __attribute__((ext_vector_type(8))) short s16x8;
typedef __attribute__((ext_vector_type(4))) float f32x4;

#define MFMA16(a,b,c) __builtin_amdgcn_mfma_f32_16x16x32_bf16(a,b,c,0,0,0)

__device__ __forceinline__ u16 f2bf(float f){
  u32 u = __builtin_bit_cast(u32, f);
  return (u16)((u + 0x7FFFu + ((u >> 16) & 1u)) >> 16);
}
__device__ __forceinline__ float b2f(u16 s){
  u32 u = ((u32)s) << 16;
  return __builtin_bit_cast(float, u);
}
__device__ __forceinline__ void async16(const void* g, void* l){
  __builtin_amdgcn_global_load_lds((const __attribute__((address_space(1))) u32*)g,
                                   (__attribute__((address_space(3))) u32*)l, 16, 0, 0);
}

// B=4, N=4096, C=512, H=8, d=64, K=64. Tokens M=16384, out-channels OC=2048.
// QKVV ws layout: [o][m], o = g*512 + h*64 + dd (g: q,k,vCA,vSA), m = b*4096 + n.
// 64-wide bf16 LDS tiles use slot-XOR swizzle: 16B-slot s at row r lives at s ^ (r&7).
// 32-wide tiles (k_gemm) use s ^ ((r>>1)&3)  -> exact 2-way (free) bank aliasing.

// ---- kernel 0: convert x,W -> bf16; EF -> bf16 transposed [64][4096] ----
__global__ __launch_bounds__(256) void k_convert(const float4* __restrict__ x4,
                                                 const float4* __restrict__ w4,
                                                 const float* __restrict__ EF,
                                                 u16* __restrict__ Xb, u16* __restrict__ Wb,
                                                 u16* __restrict__ EFt){
  int i = blockIdx.x * 256 + threadIdx.x;
  if (i < 2097152){
    float4 v = x4[i];
    u32 lo = (u32)f2bf(v.x) | ((u32)f2bf(v.y) << 16);
    u32 hi = (u32)f2bf(v.z) | ((u32)f2bf(v.w) << 16);
    *(uint2*)(&Xb[(size_t)i*4]) = make_uint2(lo, hi);
  } else if (i < 2097152 + 262144){
    int j = i - 2097152;
    float4 v = w4[j];
    u32 lo = (u32)f2bf(v.x) | ((u32)f2bf(v.y) << 16);
    u32 hi = (u32)f2bf(v.z) | ((u32)f2bf(v.w) << 16);
    *(uint2*)(&Wb[(size_t)j*4]) = make_uint2(lo, hi);
  } else if (i < 2097152 + 262144 + 262144){
    int j = i - 2097152 - 262144;
    int kk = j >> 12, nn = j & 4095;
    EFt[(size_t)kk*4096 + nn] = f2bf(EF[(size_t)nn*64 + kk]);
  }
}

// ---- kernel 1: QKVV GEMM, Out[o][m] = sum_c Wb[o][c]*Xb[m][c], bf16 out ----
// XCD-swizzled grid (2048%8==0) + slot-XOR LDS swizzle on [128][32] tiles.
__global__ __launch_bounds__(256) void k_gemm(const u16* __restrict__ Wb,
                                              const u16* __restrict__ Xb,
                                              u16* __restrict__ Out){
  __shared__ u16 smA[128*32];
  __shared__ u16 smB[128*32];
  int bid = blockIdx.x;
  int sbid = (bid & 7) * 256 + (bid >> 3);     // per-XCD contiguous chunks
  int ot = sbid & 15, mt = sbid >> 4;
  int o0 = ot * 128, m0 = mt * 128;
  int t = threadIdx.x;
  int lane = t & 63, w = t >> 6;
  int wr = w >> 1, wc = w & 1;
  int l15 = lane & 15, l4 = lane >> 4;
  f32x4 acc[4][4];
#pragma unroll
  for (int a = 0; a < 4; ++a)
#pragma unroll
    for (int b = 0; b < 4; ++b) acc[a][b] = (f32x4){0.f, 0.f, 0.f, 0.f};

  for (int kt = 0; kt < 16; ++kt){
    int kb = kt * 32;
#pragma unroll
    for (int i = 0; i < 2; ++i){
      int la = t + 256 * i;
      int row = la >> 2, sl = la & 3;
      int sg = sl ^ ((row >> 1) & 3);          // pre-swizzled global source
      async16(Wb + (size_t)(o0 + row) * 512 + kb + sg * 8, &smA[la * 8]);
      async16(Xb + (size_t)(m0 + row) * 512 + kb + sg * 8, &smB[la * 8]);
    }
    __syncthreads();
    s16x8 af[4], bfr[4];
#pragma unroll
    for (int rf = 0; rf < 4; ++rf){
      int row = wr*64 + rf*16 + l15;
      af[rf] = *(const s16x8*)(&smA[row*32 + ((l4 ^ ((row >> 1) & 3)))*8]);
    }
#pragma unroll
    for (int cf = 0; cf < 4; ++cf){
      int row = wc*64 + cf*16 + l15;
      bfr[cf] = *(const s16x8*)(&smB[row*32 + ((l4 ^ ((row >> 1) & 3)))*8]);
    }
#pragma unroll
    for (int rf = 0; rf < 4; ++rf)
#pragma unroll
      for (int cf = 0; cf < 4; ++cf)
        acc[rf][cf] = MFMA16(af[rf], bfr[cf], acc[rf][cf]);
    __syncthreads();
  }
#pragma unroll
  for (int rf = 0; rf < 4; ++rf)
#pragma unroll
    for (int cf = 0; cf < 4; ++cf){
      int o = o0 + wr*64 + rf*16 + l4*4;
      int m = m0 + wc*64 + cf*16 + l15;
#pragma unroll
      for (int r = 0; r < 4; ++r) Out[(size_t)(o + r) * 16384 + m] = f2bf(acc[rf][cf][r]);
    }
}

// ---- kernel 2: reciprocal L2 norms of q,k rows over token axis (wave per row) ----
__global__ __launch_bounds__(256) void k_rnorm(const u16* __restrict__ QK,
                                               float* __restrict__ rq, float* __restrict__ rk){
  int job = blockIdx.x * 4 + (threadIdx.x >> 6);  // 4096 jobs
  int o = job >> 2, b = job & 3;
  int lane = threadIdx.x & 63;
  const u16* row = QK + (size_t)o * 16384 + (size_t)b * 4096;
  float s = 0.f;
#pragma unroll
  for (int it = 0; it < 8; ++it){
    s16x8 v = *(const s16x8*)(&row[it * 512 + lane * 8]);
#pragma unroll
    for (int j = 0; j < 8; ++j){ float f = b2f((u16)v[j]); s += f * f; }
  }
  for (int off = 32; off; off >>= 1) s += __shfl_down(s, off);
  if (lane == 0){
    float r = 1.f / fmaxf(sqrtf(s), 1e-12f);
    if (o < 512) rq[b * 512 + o] = r;
    else         rk[b * 512 + (o - 512)] = r;
  }
}

// ---- kernel 3: partial contractions over 512-token splits ----
// grid 768 = p*256 + bh*8 + s; p: 0 = q.kT, 1 = k.EF ([kk][dd]), 2 = vSA.EF ([dd][kk])
// LDS-staged [64][128] tiles, double-buffered, counted vmcnt + raw barrier.
__global__ __launch_bounds__(256) void k_acc1(const u16* __restrict__ QK,
                                              const u16* __restrict__ EFt,
                                              float* __restrict__ Pp){
  __shared__ u16 Ab[2][64*128];
  __shared__ u16 Bb[2][64*128];
  int bid = blockIdx.x;
  int p = bid >> 8;
  int rem = bid & 255;
  int bh = rem >> 3, s = rem & 7;
  int b = bh >> 3, h = bh & 7;
  int t = threadIdx.x, lane = t & 63, w = t >> 6, l15 = lane & 15, l4 = lane >> 4;
  int abase = (p == 0 ? 0 : (p == 1 ? 512 : 1536)) + h * 64;
  const u16* Aglob = QK + (size_t)abase * 16384 + (size_t)b * 4096 + s * 512;
  const u16* Bglob;
  size_t bstride;
  if (p == 0){ Bglob = QK + (size_t)(512 + h*64) * 16384 + (size_t)b * 4096 + s * 512; bstride = 16384; }
  else       { Bglob = EFt + s * 512; bstride = 4096; }
  int srow = t >> 4, sslot = t & 15;

#define STAGE_ACC(ch, buf)                                                        \
  {                                                                               \
    int n0_ = (ch) * 128;                                                         \
    _Pragma("unroll")                                                             \
    for (int c = 0; c < 4; ++c){                                                  \
      int row = c*16 + srow;                                                      \
      int sg = sslot ^ (row & 7);                                                 \
      async16(Aglob + (size_t)row * 16384 + n0_ + sg*8, &Ab[buf][row*128 + sslot*8]); \
    }                                                                             \
    _Pragma("unroll")                                                             \
    for (int c = 0; c < 4; ++c){                                                  \
      int row = c*16 + srow;                                                      \
      int sg = sslot ^ (row & 7);                                                 \
      async16(Bglob + (size_t)row * bstride + n0_ + sg*8, &Bb[buf][row*128 + sslot*8]); \
    }                                                                             \
  }

  f32x4 acc[4];
#pragma unroll
  for (int c = 0; c < 4; ++c) acc[c] = (f32x4){0.f,0.f,0.f,0.f};

  STAGE_ACC(0, 0);
#pragma unroll
  for (int ch = 0; ch < 4; ++ch){
    int buf = ch & 1;
    if (ch < 3){
      STAGE_ACC(ch + 1, buf ^ 1);
      asm volatile("s_waitcnt vmcnt(8)" ::: "memory");
    } else {
      asm volatile("s_waitcnt vmcnt(0)" ::: "memory");
    }
    __builtin_amdgcn_s_barrier();
    asm volatile("" ::: "memory");
    int arow = w*16 + l15;
#pragma unroll
    for (int ks = 0; ks < 4; ++ks){
      s16x8 a = *(const s16x8*)(&Ab[buf][arow*128 + (((ks*4 + l4) ^ (arow & 7)))*8]);
#pragma unroll
      for (int cf = 0; cf < 4; ++cf){
        int brow = cf*16 + l15;
        s16x8 bb = *(const s16x8*)(&Bb[buf][brow*128 + (((ks*4 + l4) ^ (brow & 7)))*8]);
        acc[cf] = MFMA16(a, bb, acc[cf]);
      }
    }
    __builtin_amdgcn_s_barrier();
    asm volatile("" ::: "memory");
  }

  float* out = Pp + ((size_t)(bh * 3 + p) * 8 + s) * 4096;
#pragma unroll
  for (int cf = 0; cf < 4; ++cf)
#pragma unroll
    for (int r = 0; r < 4; ++r){
      int rr = w*16 + l4*4 + r;
      int cc = cf*16 + l15;
      int off = (p == 1) ? (cc * 64 + rr) : (rr * 64 + cc);
      out[off] = acc[cf][r];
    }
#undef STAGE_ACC
}

// ---- kernel 4: reduce partials; softmax(S)->Pca; kp*rq*t2->kpb; vp->vpb ----
// Outputs written PRE-SWIZZLED (slot s at row r stored at s^(r&7)) for linear gload_lds.
__global__ __launch_bounds__(256) void k_fin(const float* __restrict__ Pp,
                                             const float* __restrict__ rq,
                                             const float* __restrict__ rk,
                                             const float* __restrict__ t1,
                                             const float* __restrict__ t2,
                                             u16* __restrict__ Pca,
                                             u16* __restrict__ kpb,
                                             u16* __restrict__ vpb){
  int bh = blockIdx.x;
  int b = bh >> 3, h = bh & 7;
  int t = threadIdx.x;
  int row = t >> 2, q4 = t & 3;
  const float* base = Pp + (size_t)bh * 3 * 8 * 4096;
  float t1h = t1[h], t2h = t2[h];
  const float* rqh = rq + b*512 + h*64;
  const float* rkh = rk + b*512 + h*64;
  int sA = (((q4*2)     ^ (row & 7)) << 3);
  int sB = (((q4*2 + 1) ^ (row & 7)) << 3);

  // ---- product 0: S = q.kT -> scale -> softmax -> Pca
  {
    float v[16];
#pragma unroll
    for (int i = 0; i < 4; ++i){
      f32x4 a = (f32x4){0.f,0.f,0.f,0.f};
#pragma unroll
      for (int s = 0; s < 8; ++s)
        a += *(const f32x4*)(base + (size_t)s * 4096 + t*16 + i*4);
#pragma unroll
      for (int j = 0; j < 4; ++j) v[i*4 + j] = a[j];
    }
    float sq = rqh[row] * t1h;
#pragma unroll
    for (int e = 0; e < 16; ++e) v[e] *= sq * rkh[q4*16 + e];
    float mx = v[0];
#pragma unroll
    for (int e = 1; e < 16; ++e) mx = fmaxf(mx, v[e]);
    mx = fmaxf(mx, __shfl_xor(mx, 1));
    mx = fmaxf(mx, __shfl_xor(mx, 2));
    float sum = 0.f;
#pragma unroll
    for (int e = 0; e < 16; ++e){ v[e] = __expf(v[e] - mx); sum += v[e]; }
    sum += __shfl_xor(sum, 1);
    sum += __shfl_xor(sum, 2);
    float inv = 1.f / sum;
    s16x8 o0, o1;
#pragma unroll
    for (int e = 0; e < 8; ++e){ o0[e] = (short)f2bf(v[e] * inv); o1[e] = (short)f2bf(v[8+e] * inv); }
    *(s16x8*)(&Pca[(size_t)bh*4096 + row*64 + sA]) = o0;
    *(s16x8*)(&Pca[(size_t)bh*4096 + row*64 + sB]) = o1;
  }
  // ---- product 1: kp [kk][dd], scale rq[dd]*t2
  {
    const float* p1 = base + 8 * 4096;
    float v[16];
#pragma unroll
    for (int i = 0; i < 4; ++i){
      f32x4 a = (f32x4){0.f,0.f,0.f,0.f};
#pragma unroll
      for (int s = 0; s < 8; ++s)
        a += *(const f32x4*)(p1 + (size_t)s * 4096 + t*16 + i*4);
#pragma unroll
      for (int j = 0; j < 4; ++j) v[i*4 + j] = a[j];
    }
    s16x8 o0, o1;
#pragma unroll
    for (int e = 0; e < 8; ++e){
      o0[e] = (short)f2bf(v[e]   * rqh[q4*16 + e]     * t2h);
      o1[e] = (short)f2bf(v[8+e] * rqh[q4*16 + 8 + e] * t2h);
    }
    *(s16x8*)(&kpb[(size_t)bh*4096 + row*64 + sA]) = o0;
    *(s16x8*)(&kpb[(size_t)bh*4096 + row*64 + sB]) = o1;
  }
  // ---- product 2: vp [dd][kk], no scale
  {
    const float* p2 = base + 16 * 4096;
    float v[16];
#pragma unroll
    for (int i = 0; i < 4; ++i){
      f32x4 a = (f32x4){0.f,0.f,0.f,0.f};
#pragma unroll
      for (int s = 0; s < 8; ++s)
        a += *(const f32x4*)(p2 + (size_t)s * 4096 + t*16 + i*4);
#pragma unroll
      for (int j = 0; j < 4; ++j) v[i*4 + j] = a[j];
    }
    s16x8 o0, o1;
#pragma unroll
    for (int e = 0; e < 8; ++e){ o0[e] = (short)f2bf(v[e]); o1[e] = (short)f2bf(v[8+e]); }
    *(s16x8*)(&vpb[(size_t)bh*4096 + row*64 + sA]) = o0;
    *(s16x8*)(&vpb[(size_t)bh*4096 + row*64 + sB]) = o1;
  }
}

// ---- kernel 5: x_CA = P @ V_CA per 64-token chunk; overwrite out[b][n][h*64+dd] ----
__global__ __launch_bounds__(256) void k_ca_pv(const u16* __restrict__ QK,
                                               const u16* __restrict__ Pca,
                                               float* __restrict__ out){
  __shared__ u16 Pl[64*64];      // pre-swizzled, linear copy
  __shared__ u16 Vt[64*64];      // [j][e], swizzled, transpose-staged
  __shared__ float Sx[64*64];
  int bid = blockIdx.x;          // 2048 = bh*64 + ch
  int ch = bid & 63, bh = bid >> 6, b = bh >> 3, h = bh & 7;
  int n0 = ch * 64;
  int t = threadIdx.x, lane = t & 63, w = t >> 6, l15 = lane & 15, l4 = lane >> 4;
  {
    const u16* src = Pca + (size_t)bh * 4096;
#pragma unroll
    for (int c = 0; c < 2; ++c)
      async16(src + (c*256 + t)*8, &Pl[(c*256 + t)*8]);
  }
  const u16* Vg = QK + (size_t)(1024 + h*64) * 16384 + (size_t)b*4096 + n0;
#pragma unroll
  for (int pass = 0; pass < 2; ++pass){
    int idx = pass*256 + t;
    int e = idx >> 3, j0 = (idx & 7) * 8;
    s16x8 v = *(const s16x8*)(Vg + (size_t)e * 16384 + j0);
#pragma unroll
    for (int i = 0; i < 8; ++i){
      int j = j0 + i;
      Vt[j*64 + ((((e>>3) ^ (j & 7))) << 3) + (e & 7)] = (u16)v[i];
    }
  }
  __syncthreads();
  f32x4 acc[4];
#pragma unroll
  for (int c = 0; c < 4; ++c) acc[c] = (f32x4){0.f,0.f,0.f,0.f};
  int ar = w*16 + l15;
#pragma unroll
  for (int ks = 0; ks < 2; ++ks){
    s16x8 a = *(const s16x8*)(&Pl[ar*64 + (((ks*4 + l4) ^ (ar & 7)))*8]);
#pragma unroll
    for (int cf = 0; cf < 4; ++cf){
      int br = cf*16 + l15;
      s16x8 bb = *(const s16x8*)(&Vt[br*64 + (((ks*4 + l4) ^ (br & 7)))*8]);
      acc[cf] = MFMA16(a, bb, acc[cf]);
    }
  }
#pragma unroll
  for (int cf = 0; cf < 4; ++cf)
#pragma unroll
    for (int r = 0; r < 4; ++r){
      int d = w*16 + l4*4 + r, j = cf*16 + l15;
      Sx[j*64 + d] = acc[cf][r];
    }
  __syncthreads();
#pragma unroll
  for (int i = 0; i < 4; ++i){
    int idx = t + 256 * i;
    int j = idx >> 4, v = idx & 15;
    float4 val;
    val.x = Sx[j*64 + v*4 + 0]; val.y = Sx[j*64 + v*4 + 1];
    val.z = Sx[j*64 + v*4 + 2]; val.w = Sx[j*64 + v*4 + 3];
    *(float4*)(&out[((size_t)(b*4096 + n0 + j)) * 512 + h*64 + v*4]) = val;
  }
}

// ---- kernel 6: spatial attention per 64-token chunk; out += faithful-bug scatter ----
__global__ __launch_bounds__(256) void k_sa(const u16* __restrict__ QK,
                                            const u16* __restrict__ kpb,
                                            const u16* __restrict__ vpb,
                                            float* __restrict__ out){
  __shared__ u16 Qt[64*64];      // Q^T [j][dd] swizzled; reused as P [j][kk] swizzled
  __shared__ u16 kpl[64*64];     // [kk][dd] pre-swizzled
  __shared__ u16 vpl[64*64];     // [dd][kk] pre-swizzled
  __shared__ float Sf[64*64];    // x_SA^T staging
  int bid = blockIdx.x;          // 2048 = bh*64 + ch
  int ch = bid & 63, bh = bid >> 6, b = bh >> 3, h = bh & 7;
  int n0 = ch * 64;
  int t = threadIdx.x, lane = t & 63, w = t >> 6, l15 = lane & 15, l4 = lane >> 4;
#pragma unroll
  for (int c = 0; c < 2; ++c){
    async16(kpb + (size_t)bh*4096 + (c*256 + t)*8, &kpl[(c*256 + t)*8]);
    async16(vpb + (size_t)bh*4096 + (c*256 + t)*8, &vpl[(c*256 + t)*8]);
  }
  const u16* Qg = QK + (size_t)(h*64) * 16384 + (size_t)b*4096 + n0;
#pragma unroll
  for (int pass = 0; pass < 2; ++pass){
    int idx = pass*256 + t;
    int dd = idx >> 3, j0 = (idx & 7) * 8;
    s16x8 v = *(const s16x8*)(Qg + (size_t)dd * 16384 + j0);
#pragma unroll
    for (int i = 0; i < 8; ++i){
      int j = j0 + i;
      Qt[j*64 + ((((dd>>3) ^ (j & 7))) << 3) + (dd & 7)] = (u16)v[i];
    }
  }
  __syncthreads();
  // QK^T: C[j][kk]
  f32x4 acc[4];
#pragma unroll
  for (int c = 0; c < 4; ++c) acc[c] = (f32x4){0.f,0.f,0.f,0.f};
  int ar = w*16 + l15;
#pragma unroll
  for (int ks = 0; ks < 2; ++ks){
    s16x8 a = *(const s16x8*)(&Qt[ar*64 + (((ks*4 + l4) ^ (ar & 7)))*8]);
#pragma unroll
    for (int cf = 0; cf < 4; ++cf){
      int br = cf*16 + l15;
      s16x8 bb = *(const s16x8*)(&kpl[br*64 + (((ks*4 + l4) ^ (br & 7)))*8]);
      acc[cf] = MFMA16(a, bb, acc[cf]);
    }
  }
  // register softmax over kk (16 l15-lanes x 4 cf regs) per row j = w*16+l4*4+r
#pragma unroll
  for (int r = 0; r < 4; ++r){
    float mx = fmaxf(fmaxf(acc[0][r], acc[1][r]), fmaxf(acc[2][r], acc[3][r]));
    mx = fmaxf(mx, __shfl_xor(mx, 1));
    mx = fmaxf(mx, __shfl_xor(mx, 2));
    mx = fmaxf(mx, __shfl_xor(mx, 4));
    mx = fmaxf(mx, __shfl_xor(mx, 8));
    float sum = 0.f;
#pragma unroll
    for (int cf = 0; cf < 4; ++cf){ acc[cf][r] = __expf(acc[cf][r] - mx); sum += acc[cf][r]; }
    sum += __shfl_xor(sum, 1);
    sum += __shfl_xor(sum, 2);
    sum += __shfl_xor(sum, 4);
    sum += __shfl_xor(sum, 8);
    float inv = 1.f / sum;
#pragma unroll
    for (int cf = 0; cf < 4; ++cf) acc[cf][r] *= inv;
  }
  // write P into Qt (own band only; same-wave rows)
#pragma unroll
  for (int cf = 0; cf < 4; ++cf)
#pragma unroll
    for (int r = 0; r < 4; ++r){
      int j = w*16 + l4*4 + r;
      int kslot = cf*2 + (l15 >> 3);
      Qt[j*64 + ((kslot ^ (j & 7)) << 3) + (l15 & 7)] = f2bf(acc[cf][r]);
    }
  __syncthreads();
  // PV: C[j][dd] = sum_kk P[j][kk] * vpl[dd][kk]
  f32x4 acc2[4];
#pragma unroll
  for (int c = 0; c < 4; ++c) acc2[c] = (f32x4){0.f,0.f,0.f,0.f};
#pragma unroll
  for (int ks = 0; ks < 2; ++ks){
    s16x8 a = *(const s16x8*)(&Qt[ar*64 + (((ks*4 + l4) ^ (ar & 7)))*8]);
#pragma unroll
    for (int cf = 0; cf < 4; ++cf){
      int br = cf*16 + l15;
      s16x8 bb = *(const s16x8*)(&vpl[br*64 + (((ks*4 + l4) ^ (br & 7)))*8]);
      acc2[cf] = MFMA16(a, bb, acc2[cf]);
    }
  }
#pragma unroll
  for (int cf = 0; cf < 4; ++cf)
#pragma unroll
    for (int r = 0; r < 4; ++r){
      int j = w*16 + l4*4 + r, dd = cf*16 + l15;
      Sf[dd*64 + j] = acc2[cf][r];   // x_SA^T [dd][j]
    }
  __syncthreads();
  // faithful-bug scatter: out[b, dd*32768 + h*4096 + n0 + j] += x_SA[n][dd]
#pragma unroll
  for (int i = 0; i < 4; ++i){
    int idx = t + 256 * i;
    int dd = idx >> 4, v = idx & 15;
    size_t p = (size_t)b*2097152 + (size_t)dd*32768 + (size_t)h*4096 + n0 + v*4;
    float4 cur = *(float4*)(&out[p]);
    cur.x += Sf[dd*64 + v*4 + 0]; cur.y += Sf[dd*64 + v*4 + 1];
    cur.z += Sf[dd*64 + v*4 + 2]; cur.w += Sf[dd*64 + v*4 + 3];
    *(float4*)(&out[p]) = cur;
  }
}

extern "C" void kernel_launch(void* const* d_in, const int* in_sizes, int n_in,
                              void* d_out, int out_size, void* d_ws, size_t ws_size,
                              hipStream_t stream) {
  const float* x  = (const float*)d_in[0];
  const float* Wq = (const float*)d_in[1];
  const float* EF = (const float*)d_in[2];
  const float* t1 = (const float*)d_in[3];
  const float* t2 = (const float*)d_in[4];
  float* out = (float*)d_out;

  u16* Xb  = (u16*)d_ws;                 // 16384*512 (dead after k_gemm)
  u16* Wb  = Xb + 8388608;               // 2048*512
  u16* EFt = Wb + 1048576;               // 64*4096
  u16* QK  = EFt + 262144;               // 2048*16384
  float* rq  = (float*)(QK + 33554432);  // 4*512
  float* rk  = rq + 2048;                // 4*512
  u16* kpb = (u16*)(rk + 2048);          // 32*64*64 bf16 [bh][kk][dd], pre-scaled rq*t2, pre-swizzled
  u16* vpb = kpb + 131072;               // 32*64*64 bf16 [bh][dd][kk], pre-swizzled
  u16* Pca = vpb + 131072;               // 32*64*64 bf16, pre-swizzled
  float* Pp = (float*)d_ws;              // partials [bh][3][8][4096] f32, aliases Xb

  k_convert<<<10240, 256, 0, stream>>>((const float4*)x, (const float4*)Wq, EF, Xb, Wb, EFt);
  k_gemm   <<<2048, 256, 0, stream>>>(Wb, Xb, QK);
  k_rnorm  <<<1024, 256, 0, stream>>>(QK, rq, rk);
  k_acc1   <<<768,  256, 0, stream>>>(QK, EFt, Pp);
  k_fin    <<<32,   256, 0, stream>>>(Pp, rq, rk, t1, t2, Pca, kpb, vpb);
  k_ca_pv  <<<2048, 256, 0, stream>>>(QK, Pca, out);
  k_sa     <<<2048, 256, 0, stream>>>(QK, kpb, vpb, out);
}